// Round 6
// baseline (270.750 us; speedup 1.0000x reference)
//
#include <hip/hip_runtime.h>

#define D 64

typedef __attribute__((ext_vector_type(8))) short bf16x8;
typedef __attribute__((ext_vector_type(4))) float f32x4;

__device__ __forceinline__ unsigned short f2bf(float x) {
    unsigned int u = __float_as_uint(x);
    u += 0x7FFFu + ((u >> 16) & 1u);     // RNE
    return (unsigned short)(u >> 16);
}

// ---------------------------------------------------------------------------
// prep: EVERY block does cvt (grid-stride over W, then h) and then the ELL
// build (grid-stride over edges). All 2048 blocks co-resident -> the build
// phase runs with ~8192 waves instead of R5's 4096-waves-on-1/3-machine.
// ELL: pos = atomicAdd(cnt[dst]); ell[dst*stride + pos] = src.
// ---------------------------------------------------------------------------
__global__ __launch_bounds__(256) void prep_kernel(
    const float4* __restrict__ h4, ushort4* __restrict__ hb4, int nh4,
    const float4* __restrict__ W4, ushort4* __restrict__ Wb4, int nw4,
    const int4* __restrict__ esrc4, const int4* __restrict__ edst4,
    const int* __restrict__ esrc, const int* __restrict__ edst,
    int* __restrict__ cnt, int* __restrict__ ell, int stride_,
    int E4, int E)
{
    const int tid = blockIdx.x * blockDim.x + threadIdx.x;
    const int gsz = gridDim.x * blockDim.x;

    for (int i = tid; i < nw4; i += gsz) {            // W -> bf16 (tiny)
        const float4 f = W4[i];
        ushort4 o;
        o.x = f2bf(f.x); o.y = f2bf(f.y); o.z = f2bf(f.z); o.w = f2bf(f.w);
        Wb4[i] = o;
    }
    for (int i = tid; i < nh4; i += gsz) {            // h -> bf16 (BW-bound)
        const float4 f = h4[i];
        ushort4 o;
        o.x = f2bf(f.x); o.y = f2bf(f.y); o.z = f2bf(f.z); o.w = f2bf(f.w);
        hb4[i] = o;
    }
    for (int i = tid; i < E4; i += gsz) {             // ELL build
        const int4 s = esrc4[i];
        const int4 d = edst4[i];
        int p;
        p = atomicAdd(&cnt[d.x], 1); if (p < stride_) ell[(size_t)d.x * stride_ + p] = s.x;
        p = atomicAdd(&cnt[d.y], 1); if (p < stride_) ell[(size_t)d.y * stride_ + p] = s.y;
        p = atomicAdd(&cnt[d.z], 1); if (p < stride_) ell[(size_t)d.z * stride_ + p] = s.z;
        p = atomicAdd(&cnt[d.w], 1); if (p < stride_) ell[(size_t)d.w * stride_ + p] = s.w;
    }
    if (blockIdx.x == 0 && threadIdx.x == 0)          // E%4 tail (none here)
        for (int e = E4 * 4; e < E; ++e) {
            const int dd = edst[e];
            const int p = atomicAdd(&cnt[dd], 1);
            if (p < stride_) ell[(size_t)dd * stride_ + p] = esrc[e];
        }
}

// ---------------------------------------------------------------------------
// gather: wave = NG groups x GW lanes; group g owns one node entirely.
//   bf16 path: GW=8, lane covers 8 features (16B int4 load = full row/group)
//   f32 path : GW=16, lane covers 4 features (16B float4)
// All slot-ids prefetched into static-indexed regs up front, then a fully
// unrolled chain of independent 16B row loads (up to 64 in flight/group).
// Mean written as bf16 (MB16, same rounding gemm did before) or fp32.
// ---------------------------------------------------------------------------
template <bool HB16, bool MB16>
__global__ __launch_bounds__(256) void gather_kernel(
    const void* __restrict__ hsrc,
    const int* __restrict__ ell,
    const int* __restrict__ cnt,
    void* __restrict__ mdst,
    int stride_, int N)
{
    constexpr int GW    = HB16 ? 8 : 16;   // lanes per group
    constexpr int NG    = 64 / GW;         // nodes per wave
    constexpr int FPL   = HB16 ? 8 : 4;    // features per lane
    constexpr int MAXCH = 64 / GW;         // max slot-chunks (stride<=64)

    const int lane = threadIdx.x & 63;
    const int g    = lane / GW;
    const int gl   = lane % GW;
    const int node = ((blockIdx.x * blockDim.x + threadIdx.x) >> 6) * NG + g;
    if (node >= N) return;

    const int degT = cnt[node];            // group-uniform
    const int deg  = min(degT, stride_);
    const int nch  = (deg + GW - 1) / GW;
    const size_t rb = (size_t)node * stride_;

    int sl[MAXCH];                         // static-indexed -> registers
    #pragma unroll
    for (int c = 0; c < MAXCH; ++c)
        sl[c] = (c < nch) ? ell[rb + c * GW + gl] : 0;

    float a[FPL];
    #pragma unroll
    for (int i = 0; i < FPL; ++i) a[i] = 0.f;

    const unsigned short* __restrict__ hb = (const unsigned short*)hsrc;
    const float*          __restrict__ hf = (const float*)hsrc;

    #pragma unroll
    for (int c = 0; c < MAXCH; ++c) {
        if (c < nch) {
            const int rem = deg - c * GW;  // >0, group-uniform
            #pragma unroll
            for (int j = 0; j < GW; ++j) {
                if (j < rem) {
                    const int s = __shfl(sl[c], j, GW);
                    if constexpr (HB16) {
                        const int4 v = *(const int4*)(hb + (size_t)s * D + gl * 8);
                        a[0] += __uint_as_float((unsigned)v.x << 16);
                        a[1] += __uint_as_float((unsigned)v.x & 0xffff0000u);
                        a[2] += __uint_as_float((unsigned)v.y << 16);
                        a[3] += __uint_as_float((unsigned)v.y & 0xffff0000u);
                        a[4] += __uint_as_float((unsigned)v.z << 16);
                        a[5] += __uint_as_float((unsigned)v.z & 0xffff0000u);
                        a[6] += __uint_as_float((unsigned)v.w << 16);
                        a[7] += __uint_as_float((unsigned)v.w & 0xffff0000u);
                    } else {
                        const float4 v = *(const float4*)(hf + (size_t)s * D + gl * 4);
                        a[0] += v.x; a[1] += v.y; a[2] += v.z; a[3] += v.w;
                    }
                }
            }
        }
    }

    const float inv = (degT > 0) ? 1.f / (float)degT : 0.f;
    #pragma unroll
    for (int i = 0; i < FPL; ++i) a[i] *= inv;

    if constexpr (MB16) {
        unsigned short* mb = (unsigned short*)mdst;
        int4 o;
        o.x = (int)(((unsigned)f2bf(a[1]) << 16) | f2bf(a[0]));
        o.y = (int)(((unsigned)f2bf(a[3]) << 16) | f2bf(a[2]));
        o.z = (int)(((unsigned)f2bf(a[5]) << 16) | f2bf(a[4]));
        o.w = (int)(((unsigned)f2bf(a[7]) << 16) | f2bf(a[6]));
        *(int4*)(mb + (size_t)node * D + gl * 8) = o;
    } else {
        float* mf = (float*)mdst;
        if constexpr (HB16) {
            float4 o0 = {a[0], a[1], a[2], a[3]};
            float4 o1 = {a[4], a[5], a[6], a[7]};
            *(float4*)(mf + (size_t)node * D + gl * 8)     = o0;
            *(float4*)(mf + (size_t)node * D + gl * 8 + 4) = o1;
        } else {
            float4 o = {a[0], a[1], a[2], a[3]};
            *(float4*)(mf + (size_t)node * D + gl * 4) = o;
        }
    }
}

// ---------------------------------------------------------------------------
// gemm: out[n][j] = relu(mean[n][:] . W[j][:] + b[j]), 0 where deg==0.
// One 16-row tile per wave. mfma_f32_16x16x32_bf16 (layouts m89-verified,
// R5-passed). A from bf16 ws (MB16) or fp32 in-place on d_out.
// ---------------------------------------------------------------------------
template <bool MB16>
__global__ __launch_bounds__(256) void gemm_kernel(
    const void* __restrict__ msrc,
    float* __restrict__ outp,
    const unsigned short* __restrict__ Wb,
    const float* __restrict__ bias,
    const int* __restrict__ cnt,
    int N)
{
    const int lane = threadIdx.x & 63;
    const int wv   = (blockIdx.x * blockDim.x + threadIdx.x) >> 6;
    const int n0   = wv * 16;
    if (n0 >= N) return;

    const int r16 = lane & 15;
    const int kq  = lane >> 4;

    int arow = n0 + r16;
    if (arow >= N) arow = N - 1;           // benign (N%16==0 here)

    bf16x8 afr[2];
    if constexpr (MB16) {
        const unsigned short* mb = (const unsigned short*)msrc;
        #pragma unroll
        for (int ks = 0; ks < 2; ++ks)
            afr[ks] = *(const bf16x8*)(mb + (size_t)arow * D + ks * 32 + kq * 8);
    } else {
        const float* mf = (const float*)msrc;
        #pragma unroll
        for (int ks = 0; ks < 2; ++ks) {
            const float* ap = mf + (size_t)arow * D + ks * 32 + kq * 8;
            const float4 f0 = *(const float4*)ap;
            const float4 f1 = *(const float4*)(ap + 4);
            bf16x8 a;
            a[0] = (short)f2bf(f0.x); a[1] = (short)f2bf(f0.y);
            a[2] = (short)f2bf(f0.z); a[3] = (short)f2bf(f0.w);
            a[4] = (short)f2bf(f1.x); a[5] = (short)f2bf(f1.y);
            a[6] = (short)f2bf(f1.z); a[7] = (short)f2bf(f1.w);
            afr[ks] = a;
        }
    }

    int dmask[4];
    #pragma unroll
    for (int r = 0; r < 4; ++r) {
        const int node = n0 + kq * 4 + r;
        dmask[r] = (node < N) ? cnt[node] : 0;
    }

    #pragma unroll
    for (int cb = 0; cb < 4; ++cb) {
        const unsigned short* wp = Wb + (size_t)(cb * 16 + r16) * D + kq * 8;
        const bf16x8 b0 = *(const bf16x8*)wp;
        const bf16x8 b1 = *(const bf16x8*)(wp + 32);
        f32x4 acc = {0.f, 0.f, 0.f, 0.f};
        acc = __builtin_amdgcn_mfma_f32_16x16x32_bf16(afr[0], b0, acc, 0, 0, 0);
        acc = __builtin_amdgcn_mfma_f32_16x16x32_bf16(afr[1], b1, acc, 0, 0, 0);

        const float bb = bias[cb * 16 + r16];
        #pragma unroll
        for (int r = 0; r < 4; ++r) {
            const int node = n0 + kq * 4 + r;
            if (node < N) {
                const float val = acc[r] + bb;
                outp[(size_t)node * D + cb * 16 + r16] =
                    (dmask[r] > 0) ? fmaxf(val, 0.f) : 0.f;
            }
        }
    }
}

// ---------------------------------------------------------------------------
// ws: cnt[N] | ell[N*stride] | Wb[D*D bf16] | hb[N*D bf16]? | mb[N*D bf16]?
// Tiers by ws_size (R5 proved ws >= 38.8MB, so tier C at worst):
//   A: stride 64, bf16 h, bf16 means (51.6 MB)
//   B: stride 48, bf16 h, bf16 means (45.2 MB)
//   C: stride 48, bf16 h, means fp32 in d_out (32.4 MB)
//   D: stride 48, f32 h, means fp32 in d_out (19.6 MB)
// ---------------------------------------------------------------------------
extern "C" void kernel_launch(void* const* d_in, const int* in_sizes, int n_in,
                              void* d_out, int out_size, void* d_ws, size_t ws_size,
                              hipStream_t stream) {
    const float* h    = (const float*)d_in[0];
    const int*   esrc = (const int*)d_in[1];
    const int*   edst = (const int*)d_in[2];
    const float* W    = (const float*)d_in[3];
    const float* b    = (const float*)d_in[4];

    const int N  = in_sizes[0] / D;
    const int E  = in_sizes[1];
    const int E4 = E >> 2;

    float* out = (float*)d_out;

    auto need = [&](int st, bool hb, bool mb) {
        return (size_t)N * 4 + (size_t)N * st * 4 + (size_t)D * D * 2
             + (hb ? (size_t)N * D * 2 : 0) + (mb ? (size_t)N * D * 2 : 0);
    };
    int stride_; bool HB, MB;
    if      (ws_size >= need(64, true,  true))  { stride_ = 64; HB = true;  MB = true;  }
    else if (ws_size >= need(48, true,  true))  { stride_ = 48; HB = true;  MB = true;  }
    else if (ws_size >= need(48, true,  false)) { stride_ = 48; HB = true;  MB = false; }
    else                                        { stride_ = 48; HB = false; MB = false; }

    int*            cnt = (int*)d_ws;                                   // [N]
    int*            ell = cnt + N;                                      // [N*stride]
    unsigned short* Wb  = (unsigned short*)(ell + (size_t)N * stride_); // [D*D]
    unsigned short* hb  = Wb + (size_t)D * D;                           // [N*D]?
    unsigned short* mb  = hb + (size_t)N * D;                           // [N*D]?

    hipMemsetAsync(cnt, 0, (size_t)N * sizeof(int), stream);

    prep_kernel<<<2048, 256, 0, stream>>>(
        (const float4*)h, (ushort4*)hb, HB ? N * D / 4 : 0,
        (const float4*)W, (ushort4*)Wb, D * D / 4,
        (const int4*)esrc, (const int4*)edst, esrc, edst,
        cnt, ell, stride_, E4, E);

    const int NG = HB ? 8 : 4;                       // nodes per wave
    const int gWaves  = (N + NG - 1) / NG;
    const int gBlocks = (gWaves + 3) / 4;
    if (HB && MB)
        gather_kernel<true,  true ><<<gBlocks, 256, 0, stream>>>(hb, ell, cnt, mb,  stride_, N);
    else if (HB)
        gather_kernel<true,  false><<<gBlocks, 256, 0, stream>>>(hb, ell, cnt, out, stride_, N);
    else
        gather_kernel<false, false><<<gBlocks, 256, 0, stream>>>(h,  ell, cnt, out, stride_, N);

    const int tiles = (N + 15) / 16;
    const int mBlocks = (tiles + 3) / 4;
    if (MB)
        gemm_kernel<true ><<<mBlocks, 256, 0, stream>>>(mb,  out, Wb, b, cnt, N);
    else
        gemm_kernel<false><<<mBlocks, 256, 0, stream>>>(out, out, Wb, b, cnt, N);
}